// Round 14
// baseline (231.085 us; speedup 1.0000x reference)
//
#include <hip/hip_runtime.h>
#include <hip/hip_bf16.h>

#define DIM 256
#define HW  1024  // 32*32

typedef __attribute__((ext_vector_type(8))) short short8;
typedef __attribute__((ext_vector_type(4))) float floatx4;
typedef __attribute__((ext_vector_type(16))) float floatx16;
typedef __attribute__((address_space(1))) const unsigned int g_u32;
typedef __attribute__((address_space(3))) unsigned int l_u32;

__device__ inline unsigned short f2bf(float f) {
  union { float f; unsigned u; } v;
  v.f = f;
  unsigned u = v.u;
  u += 0x7fffu + ((u >> 16) & 1u);
  return (unsigned short)(u >> 16);
}

__device__ inline float ldin(const void* p, long i, int isf32) {
  if (isf32) return ((const float*)p)[i];
  union { unsigned u; float f; } v;
  v.u = ((unsigned)((const unsigned short*)p)[i]) << 16;
  return v.f;
}

// ---------------------------------------------------------------------------
// R14 prep: coalesced two-stage weight repack (replaces the strided gather
// whose 100B-stride lane pattern amplified w7 reads ~16-25x in line traffic —
// the prime suspect for the ~144us of non-conv time).
// Per-block dtype detect (16KB L2-hot scan) replaces the serialized detect
// dispatch; the bias block publishes the flag for linear_mfma.
// wF layout (unchanged): [tap][c8(8)][co16(16)][lane(64)][j(8)],
//   co = co16*16 + (lane&15), ci = c8*32 + (lane>>4)*8 + j.
// Repack block owns (co16,c8): for each co, source w[co][c8*32..+31][0..KK-1]
// is contiguous 32*KK floats -> coalesced load into LDS; outputs are KK
// coalesced 512-element chunks. Identity (by substitution):
//   Wl[(co_l*32+ci_s)*KK+tap] == w[(co*256+ci)*KK+tap]  with co=co16*16+co_l,
//   ci=c8*32+ci_s; dst index i==j+lane*8 matches old idx exactly.
// ---------------------------------------------------------------------------
__device__ inline int detect_f32(const unsigned short* __restrict__ xr,
                                 int* cnt) {
  if (threadIdx.x == 0) *cnt = 0;
  __syncthreads();
  int local = 0;
  for (int i = threadIdx.x; i < 8192; i += 256) {
    unsigned short u = xr[i];
    if ((u & 0x7F80u) == 0x7F80u) local++;
  }
  if (local) atomicAdd(cnt, local);
  __syncthreads();
  return (*cnt > 0) ? 1 : 0;
}

__device__ inline void frag_repack2(const void* __restrict__ w,
                                    unsigned short* __restrict__ wF, int KK,
                                    int slice, float* __restrict__ Wl,
                                    int isf32) {
  const int t = threadIdx.x;
  const int co16 = slice & 15;
  const int c8   = slice >> 4;
  const int RE = 32 * KK;  // elems per co row (contiguous in source)
  for (int r = 0; r < 16; ++r) {
    const long base = ((long)((co16 * 16 + r) * 256 + c8 * 32)) * KK;
    for (int i = t; i < RE; i += 256) Wl[r * RE + i] = ldin(w, base + i, isf32);
  }
  __syncthreads();
  for (int tap = 0; tap < KK; ++tap) {
    unsigned short* dst = wF + ((((tap << 3) + c8) << 4) + co16) * 512;
    for (int i = t; i < 512; i += 256) {
      const int lane = i >> 3, j = i & 7;
      const int col = lane & 15;
      const int cis = ((lane >> 4) << 3) + j;
      dst[i] = f2bf(Wl[(col * 32 + cis) * KK + tap]);
    }
  }
}

__global__ __launch_bounds__(256) void prep_kernel(
    const void* __restrict__ x,  const void* __restrict__ w3,
    const void* __restrict__ b3, const void* __restrict__ w5,
    const void* __restrict__ b5, const void* __restrict__ w7,
    const void* __restrict__ b7, const void* __restrict__ wp,
    unsigned short* __restrict__ xbf,
    unsigned short* __restrict__ wF3, unsigned short* __restrict__ wF5,
    unsigned short* __restrict__ wF7, unsigned short* __restrict__ wpF,
    float* __restrict__ bc,  // [3][256] q,v,k
    int* __restrict__ flag) {
  __shared__ float Wl[12800];  // 16co x 32ci x 25tap (51.2 KB max)
  __shared__ int cnt;
  const int isf32 = detect_f32((const unsigned short*)x, &cnt);
  const int bid = blockIdx.x;
  const int t = threadIdx.x;
  if (bid < 2048) {            // x -> bf16, 4 elem/thread
    const int i = (bid * 256 + t) * 4;
    if (isf32) {
      const float4 v = *(const float4*)((const float*)x + i);
      ushort4 o;
      o.x = f2bf(v.x); o.y = f2bf(v.y); o.z = f2bf(v.z); o.w = f2bf(v.w);
      *(ushort4*)(xbf + i) = o;
    } else {
      *(ushort4*)(xbf + i) = *(const ushort4*)((const unsigned short*)x + i);
    }
  } else if (bid < 2176) {
    frag_repack2(w7, wF7, 25, bid - 2048, Wl, isf32);
  } else if (bid < 2304) {
    frag_repack2(w5, wF5, 9, bid - 2176, Wl, isf32);
  } else if (bid < 2432) {
    frag_repack2(w3, wF3, 1, bid - 2304, Wl, isf32);
  } else if (bid < 2560) {
    frag_repack2(wp, wpF, 1, bid - 2432, Wl, isf32);
  } else {                     // biases (q=b3, v=b5, k=b7) + publish flag
#pragma unroll
    for (int r = 0; r < 3; ++r) {
      const int i = r * 256 + t;
      const void* src = (i < 256) ? b3 : (i < 512) ? b5 : b7;
      bc[i] = ldin(src, i & 255, isf32);
    }
    if (t == 0) *flag = isf32;
  }
}

// ---------------------------------------------------------------------------
// R13-verified FUSED q/v/k conv (byte-identical). LDS-fed tap loop; B staged
// via global_load_lds(16B) (zero VGPR round-trip; R12's register staging
// spilled to scratch = 281 MB HBM writes). At the LDS-pipe roofline for this
// fragment scheme (~85 b128/wave/chunk ≈ 2.8 GB @ 69 TB/s + conflicts).
// Geometry: Tm=128 x Tco=16; grid 1024, 2 blocks/CU (LDS 58.5 KB).
// Attention coords (R2/R11-verified): slab=(b<<4)+(co>>4), m=(co&15)*64+(n>>4),
//   d=n&15;  q/k rows: (slab<<14)+((co&15)<<10)+n ;  v (V^T):
//   (slab<<14)+((n&15)<<10)+((co&15)<<6)+(n>>4)
// ---------------------------------------------------------------------------
__global__ __launch_bounds__(256, 2) void convqkv_kernel(
    const unsigned short* __restrict__ xbf,
    const unsigned short* __restrict__ wFq,  // 1 tap
    const unsigned short* __restrict__ wFv,  // 9 taps
    const unsigned short* __restrict__ wFk,  // 25 taps
    const float* __restrict__ bc,            // [3][256] q,v,k
    unsigned short* __restrict__ qOut,
    unsigned short* __restrict__ vOut,
    unsigned short* __restrict__ kOut) {
  constexpr int WC = 36;          // halo cols (32 + 2*2)
  constexpr int LOADS = 288 * 4;  // 1152 halo dwordx4 loads (288 cells)
  __shared__ unsigned short Xs[288 * 40];  // halo [cell][32ci pad40]  23 KB
  __shared__ unsigned short Bs[36 * 512];  // B [tap35+1][lane64][8]   36 KB
  const int t    = threadIdx.x;
  const int bid  = blockIdx.x;
  const int cog0 = bid & 15;           // single co16 tile (16 co)
  const int co0  = cog0 << 4;
  const int m0   = (bid >> 4) << 7;    // 128 positions
  const int b    = m0 >> 10;
  const int n0   = m0 & 1023;
  const int r0   = n0 >> 5;            // first of 4 image rows
  const int wv   = t >> 6;             // wave = image row r0+wv
  const int lane = t & 63;
  const int l15  = lane & 15;
  const int quad = lane >> 4;

  floatx4 aq[2] = {}, av[2] = {}, ak[2] = {};

  for (int c8 = 0; c8 < 8; ++c8) {
    // ---- halo loads into registers (R9/R11-proven, 20 VGPRs) ----
    uint4 xreg[5];
    int idv[5];
#pragma unroll
    for (int rr = 0; rr < 5; ++rr) {
      const int id = rr * 256 + t;
      const int cell = id >> 2, part = id & 3;
      const int hr = cell / WC, wc = cell - hr * WC;
      const int xr = r0 + hr - 2, xc = wc - 2;
      const bool ok = (id < LOADS) && ((unsigned)xr < 32u) &&
                      ((unsigned)xc < 32u);
      const int cr = xr < 0 ? 0 : (xr > 31 ? 31 : xr);
      const int cc = xc < 0 ? 0 : (xc > 31 ? 31 : xc);
      uint4 v = *(const uint4*)&xbf[(((b * 32 + cr) * 32 + cc) << 8) +
                                    (c8 << 5) + (part << 3)];
      if (!ok) v = make_uint4(0, 0, 0, 0);
      xreg[rr] = v;
      idv[rr] = id;
    }
    __syncthreads();  // ALL waves done reading previous chunk's Xs/Bs
    // ---- B: 35 taps via global_load_lds (no VGPR round-trip) ----
#pragma unroll
    for (int rr = 0; rr < 9; ++rr) {
      const int tap = (rr << 2) + wv;
      if (tap < 35) {
        const unsigned short* src;
        if (tap < 25) {
          src = &wFk[((((tap << 3) + c8) << 4) + cog0) * 512];
        } else if (tap < 34) {
          src = &wFv[(((((tap - 25) << 3) + c8) << 4) + cog0) * 512];
        } else {
          src = &wFq[((c8 << 4) + cog0) * 512];
        }
        __builtin_amdgcn_global_load_lds((g_u32*)(src + (lane << 3)),
                                         (l_u32*)&Bs[tap << 9], 16, 0, 0);
      }
    }
    // ---- halo regs -> LDS ----
#pragma unroll
    for (int rr = 0; rr < 5; ++rr) {
      const int id = idv[rr];
      if (id < LOADS)
        *(uint4*)&Xs[(id >> 2) * 40 + ((id & 3) << 3)] = xreg[rr];
    }
    __syncthreads();  // drains vmcnt (glds) + lgkm (ds_writes): all ready

    // ---- tap loop: pure LDS + MFMA, no global, no barriers ----
#pragma unroll
    for (int tap = 0; tap < 25; ++tap) {
      const int kh = tap / 5, kw = tap % 5;
      const bool vv = (kh >= 1 && kh <= 3 && kw >= 1 && kw <= 3);
      const unsigned short* xs =
          &Xs[((wv + kh) * WC + l15 + kw) * 40 + (quad << 3)];
      const short8 a0 = *(const short8*)xs;
      const short8 a1 = *(const short8*)(xs + 16 * 40);
      const short8 kb = *(const short8*)&Bs[(tap << 9) + (lane << 3)];
      ak[0] = __builtin_amdgcn_mfma_f32_16x16x32_bf16(a0, kb, ak[0], 0, 0, 0);
      ak[1] = __builtin_amdgcn_mfma_f32_16x16x32_bf16(a1, kb, ak[1], 0, 0, 0);
      if (vv) {
        const int vt = (kh - 1) * 3 + (kw - 1);
        const short8 vb =
            *(const short8*)&Bs[((25 + vt) << 9) + (lane << 3)];
        av[0] = __builtin_amdgcn_mfma_f32_16x16x32_bf16(a0, vb, av[0],
                                                        0, 0, 0);
        av[1] = __builtin_amdgcn_mfma_f32_16x16x32_bf16(a1, vb, av[1],
                                                        0, 0, 0);
      }
      if (tap == 12) {
        const short8 qb = *(const short8*)&Bs[(34 << 9) + (lane << 3)];
        aq[0] = __builtin_amdgcn_mfma_f32_16x16x32_bf16(a0, qb, aq[0],
                                                        0, 0, 0);
        aq[1] = __builtin_amdgcn_mfma_f32_16x16x32_bf16(a1, qb, aq[1],
                                                        0, 0, 0);
      }
    }
  }
  // ---- epilogues (byte-identical algebra to R11-R13's PASSED kernels) ----
#pragma unroll
  for (int mi = 0; mi < 2; ++mi) {
    const int co = co0 + l15;
    const int slab = (b << 4) + (co >> 4);
    const int clo = co & 15;
    const int nb = n0 + (wv << 5) + (mi << 4) + (quad << 2);
    {
      const float bj = bc[co];
      floatx4 a = aq[mi];
      ushort4 pk4;
      pk4.x = f2bf(a[0] + bj); pk4.y = f2bf(a[1] + bj);
      pk4.z = f2bf(a[2] + bj); pk4.w = f2bf(a[3] + bj);
      *(ushort4*)&qOut[(slab << 14) + (clo << 10) + nb] = pk4;
    }
    {
      const float bj = bc[512 + co];
      floatx4 a = ak[mi];
      ushort4 pk4;
      pk4.x = f2bf(a[0] + bj); pk4.y = f2bf(a[1] + bj);
      pk4.z = f2bf(a[2] + bj); pk4.w = f2bf(a[3] + bj);
      *(ushort4*)&kOut[(slab << 14) + (clo << 10) + nb] = pk4;
    }
    {
      const float bj = bc[256 + co];
      floatx4 a = av[mi];
      const int base = (slab << 14) + (clo << 6);
#pragma unroll
      for (int i = 0; i < 4; ++i) {
        const int n = nb + i;
        vOut[base + ((n & 15) << 10) + (n >> 4)] = f2bf(a[i] + bj);
      }
    }
  }
}

// ---------------------------------------------------------------------------
// MFMA attention per (b,h) slab: softmax(Q K^T * 0.25) V.  [R5-verified]
//   qg, kg : bf16 [slab][1024 m][16 d];  vg : bf16 [slab][16 d][1024 m]
//   out2   : bf16 [8][1024 m][256], c = h*16+d
// ---------------------------------------------------------------------------
__global__ __launch_bounds__(256) void attn_mfma_kernel(
    const unsigned short* __restrict__ qg,
    const unsigned short* __restrict__ kg,
    const unsigned short* __restrict__ vg,
    unsigned short* __restrict__ out2) {
  __shared__ __align__(16) unsigned short Kc[16384];     // [key][16]
  __shared__ __align__(16) unsigned short Vt[16][1032];  // [d][key], padded
  __shared__ __align__(16) unsigned short Pb[4][32][40]; // per-wave P
  __shared__ float lb[4][32];
  const int t    = threadIdx.x;
  const int w    = t >> 6;
  const int lane = t & 63;
  const int slab = blockIdx.x >> 3;
  const int rb   = blockIdx.x & 7;
  const int b = slab >> 4;
  const int h = slab & 15;
  const int l31  = lane & 31;
  const int hl   = lane >> 5;
  const int l15  = lane & 15;
  const int quad = lane >> 4;

#pragma unroll
  for (int j = 0; j < 8; ++j) {
    const int id = (j << 8) + t;
    const int e  = id << 3;
    *(uint4*)&Kc[e] = *(const uint4*)&kg[(slab << 14) + e];
    const int d = e >> 10, ky = e & 1023;
    *(uint4*)&Vt[d][ky] = *(const uint4*)&vg[(slab << 14) + e];
  }

  const int row0 = (rb << 7) + (w << 5);
  const short8 qa =
      *(const short8*)&qg[(slab << 14) + ((row0 + l31) << 4) + (hl << 3)];

  float lsum[16] = {};
  floatx4 acco[2] = {};
  const float sc = 0.25f * 1.4426950408889634f;

  __syncthreads();

  for (int kc = 0; kc < 1024; kc += 32) {
    const short8 kb = *(const short8*)&Kc[((kc + l31) << 4) + (hl << 3)];
    floatx16 s = {};
    s = __builtin_amdgcn_mfma_f32_32x32x16_bf16(qa, kb, s, 0, 0, 0);
#pragma unroll
    for (int r = 0; r < 16; ++r) {
      const float e = exp2f(s[r] * sc);
      lsum[r] += e;
      const int row = (r & 3) + ((r >> 2) << 3) + (hl << 2);
      Pb[w][row][l31] = f2bf(e);
    }
    const short8 vb = *(const short8*)&Vt[l15][kc + (quad << 3)];
#pragma unroll
    for (int tt = 0; tt < 2; ++tt) {
      const short8 pa = *(const short8*)&Pb[w][(tt << 4) + l15][quad << 3];
      acco[tt] =
          __builtin_amdgcn_mfma_f32_16x16x32_bf16(pa, vb, acco[tt], 0, 0, 0);
    }
  }

#pragma unroll
  for (int r = 0; r < 16; ++r) {
    float lv = lsum[r];
    lv += __shfl_xor(lv, 1, 64);
    lv += __shfl_xor(lv, 2, 64);
    lv += __shfl_xor(lv, 4, 64);
    lv += __shfl_xor(lv, 8, 64);
    lv += __shfl_xor(lv, 16, 64);
    lsum[r] = lv;
  }
  {
    const int rr = l31;
    if (((rr >> 2) & 1) == hl) {
      const int reg = (rr & 3) + ((rr >> 3) << 2);
      lb[w][rr] = 1.0f / lsum[reg];
    }
  }
#pragma unroll
  for (int tt = 0; tt < 2; ++tt) {
#pragma unroll
    for (int r = 0; r < 4; ++r) {
      const int nloc = (tt << 4) + (quad << 2) + r;
      const float val = acco[tt][r] * lb[w][nloc];
      const int n = row0 + nloc;
      out2[(((b << 10) + n) << 8) + (h << 4) + l15] = f2bf(val);
    }
  }
}

// ---------------------------------------------------------------------------
// Final linear, MFMA bf16, with one-chunk-ahead B register prefetch.
// ---------------------------------------------------------------------------
__global__ __launch_bounds__(256) void linear_mfma_kernel(
    const unsigned short* __restrict__ inp,  // bf16 [8192][256]
    const unsigned short* __restrict__ wpF,  // fragment order
    void* __restrict__ out, const int* __restrict__ flag) {
  __shared__ unsigned short As[64 * 40];
  const int isf32 = *flag;
  const int t   = threadIdx.x;
  const int m0  = blockIdx.x << 6;
  const int co0 = blockIdx.y << 6;
  const int wv   = t >> 6;
  const int lane = t & 63;
  const int wm = (wv & 1) << 5;
  const int wn = (wv >> 1) << 5;
  const int l15  = lane & 15;
  const int quad = lane >> 4;
  const int cogb = (co0 >> 4) + (wn >> 4);
  const int rowS = t >> 2;
  const int partS = t & 3;

  floatx4 acc[2][2] = {};

  short8 cb0, cb1;
  {
    const unsigned short* wptr = &wpF[(cogb << 9) + (lane << 3)];
    cb0 = *(const short8*)wptr;
    cb1 = *(const short8*)(wptr + 512);
  }
  for (int c8 = 0; c8 < 8; ++c8) {
    const uint4 v = *(const uint4*)&inp[((m0 + rowS) << 8) + (c8 << 5) +
                                        (partS << 3)];
    short8 nb0 = {}, nb1 = {};
    if (c8 + 1 < 8) {
      const unsigned short* wptr =
          &wpF[((((c8 + 1) << 4) + cogb) << 9) + (lane << 3)];
      nb0 = *(const short8*)wptr;
      nb1 = *(const short8*)(wptr + 512);
    }
    __syncthreads();
    *(uint4*)&As[rowS * 40 + (partS << 3)] = v;
    __syncthreads();
    const unsigned short* xs = &As[(wm + l15) * 40 + (quad << 3)];
    const short8 afr0 = *(const short8*)xs;
    const short8 afr1 = *(const short8*)(xs + 16 * 40);
    acc[0][0] = __builtin_amdgcn_mfma_f32_16x16x32_bf16(afr0, cb0,
                                                        acc[0][0], 0, 0, 0);
    acc[0][1] = __builtin_amdgcn_mfma_f32_16x16x32_bf16(afr0, cb1,
                                                        acc[0][1], 0, 0, 0);
    acc[1][0] = __builtin_amdgcn_mfma_f32_16x16x32_bf16(afr1, cb0,
                                                        acc[1][0], 0, 0, 0);
    acc[1][1] = __builtin_amdgcn_mfma_f32_16x16x32_bf16(afr1, cb1,
                                                        acc[1][1], 0, 0, 0);
    cb0 = nb0; cb1 = nb1;
  }
#pragma unroll
  for (int mi = 0; mi < 2; ++mi) {
#pragma unroll
    for (int ni = 0; ni < 2; ++ni) {
      const int co = co0 + wn + (ni << 4) + l15;
      const int mb = m0 + wm + (mi << 4) + (quad << 2);
      floatx4 a = acc[mi][ni];
      if (!isf32) {
        unsigned short* o16 = (unsigned short*)out;
#pragma unroll
        for (int r = 0; r < 4; ++r) o16[(mb + r) * 256 + co] = f2bf(a[r]);
      } else {
        float* o32 = (float*)out;
#pragma unroll
        for (int r = 0; r < 4; ++r) o32[(mb + r) * 256 + co] = a[r];
      }
    }
  }
}

// ---------------------------------------------------------------------------
extern "C" void kernel_launch(void* const* d_in, const int* in_sizes, int n_in,
                              void* d_out, int out_size, void* d_ws,
                              size_t ws_size, hipStream_t stream) {
  const void* x  = d_in[0];
  const void* w3 = d_in[1];
  const void* b3 = d_in[2];
  const void* w5 = d_in[3];
  const void* b5 = d_in[4];
  const void* w7 = d_in[5];
  const void* b7 = d_in[6];
  const void* wp = d_in[7];

  char* p = (char*)d_ws;
  int* flag = (int*)p;                       p += 256;
  unsigned short* xbf = (unsigned short*)p;  p += 4u * 1024 * 1024;
  unsigned short* wF3 = (unsigned short*)p;  p += 131072;
  unsigned short* wF5 = (unsigned short*)p;  p += 1179648;
  unsigned short* wF7 = (unsigned short*)p;  p += 3276800;
  unsigned short* wpF = (unsigned short*)p;  p += 131072;
  float* bc = (float*)p;                     p += 4096;     // [3][256]
  unsigned short* qc  = (unsigned short*)p;  p += 4194304;  // bf16 QK rows
  unsigned short* kT  = (unsigned short*)p;  p += 4194304;  // bf16 QK rows
  unsigned short* vT  = (unsigned short*)p;  p += 4194304;  // bf16 V^T
  unsigned short* o2b = (unsigned short*)p;  p += 4194304;  // bf16 [8192][256]

  prep_kernel<<<2561, 256, 0, stream>>>(x, w3, b3, w5, b5, w7, b7, wp, xbf,
                                        wF3, wF5, wF7, wpF, bc, flag);

  convqkv_kernel<<<1024, 256, 0, stream>>>(xbf, wF3, wF5, wF7, bc, qc, vT, kT);

  attn_mfma_kernel<<<1024, 256, 0, stream>>>(qc, kT, vT, o2b);

  dim3 lg(128, 4);
  linear_mfma_kernel<<<lg, 256, 0, stream>>>(o2b, wpF, d_out, flag);
}

// Round 15
// 195.733 us; speedup vs baseline: 1.1806x; 1.1806x over previous
//
#include <hip/hip_runtime.h>
#include <hip/hip_bf16.h>

#define DIM 256
#define HW  1024  // 32*32

typedef __attribute__((ext_vector_type(8))) short short8;
typedef __attribute__((ext_vector_type(4))) float floatx4;
typedef __attribute__((ext_vector_type(16))) float floatx16;
typedef __attribute__((address_space(1))) const unsigned int g_u32;
typedef __attribute__((address_space(3))) unsigned int l_u32;

__device__ inline unsigned short f2bf(float f) {
  union { float f; unsigned u; } v;
  v.f = f;
  unsigned u = v.u;
  u += 0x7fffu + ((u >> 16) & 1u);
  return (unsigned short)(u >> 16);
}

// ---------------------------------------------------------------------------
// Dtype detector: flag=1 if inputs are fp32, 0 if bf16 (see R2 notes).
// (R13 version restored — R14's per-block detect + big-LDS prep regressed.)
// ---------------------------------------------------------------------------
__global__ void detect_kernel(const unsigned short* __restrict__ xr,
                              int* __restrict__ flag) {
  __shared__ int cnt;
  if (threadIdx.x == 0) cnt = 0;
  __syncthreads();
  int local = 0;
  for (int i = threadIdx.x; i < 8192; i += 256) {
    unsigned short u = xr[i];
    if ((u & 0x7F80u) == 0x7F80u) local++;
  }
  if (local) atomicAdd(&cnt, local);
  __syncthreads();
  if (threadIdx.x == 0) *flag = (cnt > 0) ? 1 : 0;
}

__device__ inline float ldin(const void* p, long i, int isf32) {
  if (isf32) return ((const float*)p)[i];
  union { unsigned u; float f; } v;
  v.u = ((unsigned)((const unsigned short*)p)[i]) << 16;
  return v.f;
}

// ---------------------------------------------------------------------------
// R13 prep (restored verbatim): x->bf16, weights -> MFMA-fragment order bf16,
// biases -> fp32.
// wF layout: [tap][c8(8)][co16(16)][lane(64)][j(8)]  where
//   co = co16*16 + (lane&15), ci = c8*32 + (lane>>4)*8 + j
// ---------------------------------------------------------------------------
__device__ inline void frag_repack(const void* __restrict__ w,
                                   unsigned short* __restrict__ wF, int KK,
                                   int local_blk, int t, int isf32) {
  const int idx = local_blk * 256 + t;
  const int j    = idx & 7;
  const int lane = (idx >> 3) & 63;
  const int co16 = (idx >> 9) & 15;
  const int c8   = (idx >> 13) & 7;
  const int tap  = idx >> 16;
  const int co = (co16 << 4) | (lane & 15);
  const int ci = (c8 << 5) + ((lane >> 4) << 3) + j;
  wF[idx] = f2bf(ldin(w, (long)(co * 256 + ci) * KK + tap, isf32));
}

__global__ void prep_kernel(const void* __restrict__ x,
                            const void* __restrict__ w3,
                            const void* __restrict__ b3,
                            const void* __restrict__ w5,
                            const void* __restrict__ b5,
                            const void* __restrict__ w7,
                            const void* __restrict__ b7,
                            const void* __restrict__ wp,
                            unsigned short* __restrict__ xbf,
                            unsigned short* __restrict__ wF3,
                            unsigned short* __restrict__ wF5,
                            unsigned short* __restrict__ wF7,
                            unsigned short* __restrict__ wpF,
                            float* __restrict__ bc,  // [3][256] q,v,k
                            const int* __restrict__ flag) {
  const int isf32 = *flag;
  const int bid = blockIdx.x;
  const int t = threadIdx.x;
  if (bid < 2048) {            // x -> bf16, 4 elem/thread
    const int i = (bid * 256 + t) * 4;
    if (isf32) {
      const float4 v = *(const float4*)((const float*)x + i);
      ushort4 o;
      o.x = f2bf(v.x); o.y = f2bf(v.y); o.z = f2bf(v.z); o.w = f2bf(v.w);
      *(ushort4*)(xbf + i) = o;
    } else {
      *(ushort4*)(xbf + i) = *(const ushort4*)((const unsigned short*)x + i);
    }
  } else if (bid < 2304) {
    frag_repack(w3, wF3, 1, bid - 2048, t, isf32);
  } else if (bid < 4608) {
    frag_repack(w5, wF5, 9, bid - 2304, t, isf32);
  } else if (bid < 11008) {
    frag_repack(w7, wF7, 25, bid - 4608, t, isf32);
  } else if (bid < 11264) {
    frag_repack(wp, wpF, 1, bid - 11008, t, isf32);
  } else {                     // biases: 768 elements (q=b3, v=b5, k=b7)
#pragma unroll
    for (int r = 0; r < 3; ++r) {
      const int i = r * 256 + t;
      const void* src = (i < 256) ? b3 : (i < 512) ? b5 : b7;
      bc[i] = ldin(src, i & 255, isf32);
    }
  }
}

// ---------------------------------------------------------------------------
// R15 FUSED q/v/k conv: R13's verified structure with Tm=256 per block
// (wave owns 2 image rows = 4 A-frags/tap). LDS-read accounting (validated
// against R13's 69.7us: 10880 b128/CU @~12cyc + 7.7M conflict cyc = 67us):
// per chunk per wave now 25*4 A + 35 B = 135 b128 for 2x output -> total
// b128/CU 10880 -> 8640 (-21%), grid 512 = single residency round.
// B staged via global_load_lds(16B) (R13-verified; zero VGPR round-trip).
// LDS 71.4 KB -> 2 blocks/CU.
// Attention coords (R2/R11-verified): slab=(b<<4)+(co>>4), m=(co&15)*64+(n>>4),
//   d=n&15;  q/k rows: (slab<<14)+((co&15)<<10)+n ;  v (V^T):
//   (slab<<14)+((n&15)<<10)+((co&15)<<6)+(n>>4)
// ---------------------------------------------------------------------------
__global__ __launch_bounds__(256, 2) void convqkv_kernel(
    const unsigned short* __restrict__ xbf,
    const unsigned short* __restrict__ wFq,  // 1 tap
    const unsigned short* __restrict__ wFv,  // 9 taps
    const unsigned short* __restrict__ wFk,  // 25 taps
    const float* __restrict__ bc,            // [3][256] q,v,k
    unsigned short* __restrict__ qOut,
    unsigned short* __restrict__ vOut,
    unsigned short* __restrict__ kOut) {
  constexpr int WC = 36;            // halo cols (32 + 2*2)
  constexpr int CELLS = 12 * WC;    // 12 halo rows (8 + 2*2) = 432 cells
  constexpr int LOADS = CELLS * 4;  // 1728 halo dwordx4 loads
  __shared__ unsigned short Xs[CELLS * 40];  // halo [cell][32ci pad40] 34.6KB
  __shared__ unsigned short Bs[36 * 512];    // B [tap35+1][lane64][8]  36.9KB
  const int t    = threadIdx.x;
  const int bid  = blockIdx.x;
  const int cog0 = bid & 15;           // single co16 tile (16 co)
  const int co0  = cog0 << 4;
  const int m0   = (bid >> 4) << 8;    // 256 positions (8 image rows)
  const int b    = m0 >> 10;
  const int n0   = m0 & 1023;
  const int r0   = n0 >> 5;            // first of 8 image rows
  const int wv   = t >> 6;             // wave owns rows r0+2wv, r0+2wv+1
  const int lane = t & 63;
  const int l15  = lane & 15;
  const int quad = lane >> 4;

  floatx4 aq[4] = {}, av[4] = {}, ak[4] = {};  // frag f = rr*2+ch

  for (int c8 = 0; c8 < 8; ++c8) {
    // ---- halo loads into registers (7 x uint4 = 28 VGPR; no spill at 256) --
    uint4 xreg[7];
#pragma unroll
    for (int rr = 0; rr < 7; ++rr) {
      const int id = rr * 256 + t;
      const int cell = id >> 2, part = id & 3;
      const int hr = cell / WC, wc = cell - hr * WC;
      const int xr = r0 + hr - 2, xc = wc - 2;
      const bool ok = (id < LOADS) && ((unsigned)xr < 32u) &&
                      ((unsigned)xc < 32u);
      const int cr = xr < 0 ? 0 : (xr > 31 ? 31 : xr);
      const int cc = xc < 0 ? 0 : (xc > 31 ? 31 : xc);
      uint4 v = *(const uint4*)&xbf[(((b * 32 + cr) * 32 + cc) << 8) +
                                    (c8 << 5) + (part << 3)];
      if (!ok) v = make_uint4(0, 0, 0, 0);
      xreg[rr] = v;
    }
    __syncthreads();  // ALL waves done reading previous chunk's Xs/Bs
    // ---- B: 35 taps via global_load_lds (wave-uniform base, lane*16B) ----
#pragma unroll
    for (int rr = 0; rr < 9; ++rr) {
      const int tap = (rr << 2) + wv;
      if (tap < 35) {
        const unsigned short* src;
        if (tap < 25) {
          src = &wFk[((((tap << 3) + c8) << 4) + cog0) * 512];
        } else if (tap < 34) {
          src = &wFv[(((((tap - 25) << 3) + c8) << 4) + cog0) * 512];
        } else {
          src = &wFq[((c8 << 4) + cog0) * 512];
        }
        __builtin_amdgcn_global_load_lds((g_u32*)(src + (lane << 3)),
                                         (l_u32*)&Bs[tap << 9], 16, 0, 0);
      }
    }
    // ---- halo regs -> LDS ----
#pragma unroll
    for (int rr = 0; rr < 7; ++rr) {
      const int id = rr * 256 + t;
      if (id < LOADS)
        *(uint4*)&Xs[(id >> 2) * 40 + ((id & 3) << 3)] = xreg[rr];
    }
    __syncthreads();  // drains vmcnt (glds) + lgkm (ds_writes): all ready

    // ---- tap loop: pure LDS + MFMA, no global, no barriers ----
#pragma unroll
    for (int tap = 0; tap < 25; ++tap) {
      const int kh = tap / 5, kw = tap % 5;
      const bool vv = (kh >= 1 && kh <= 3 && kw >= 1 && kw <= 3);
      short8 a[4];
#pragma unroll
      for (int rr2 = 0; rr2 < 2; ++rr2) {
#pragma unroll
        for (int ch = 0; ch < 2; ++ch) {
          const unsigned short* xs =
              &Xs[(((wv << 1) + rr2 + kh) * WC + (ch << 4) + l15 + kw) * 40 +
                  (quad << 3)];
          a[(rr2 << 1) + ch] = *(const short8*)xs;
        }
      }
      const short8 kb = *(const short8*)&Bs[(tap << 9) + (lane << 3)];
#pragma unroll
      for (int f = 0; f < 4; ++f)
        ak[f] = __builtin_amdgcn_mfma_f32_16x16x32_bf16(a[f], kb, ak[f],
                                                        0, 0, 0);
      if (vv) {
        const int vt = (kh - 1) * 3 + (kw - 1);
        const short8 vb = *(const short8*)&Bs[((25 + vt) << 9) + (lane << 3)];
#pragma unroll
        for (int f = 0; f < 4; ++f)
          av[f] = __builtin_amdgcn_mfma_f32_16x16x32_bf16(a[f], vb, av[f],
                                                          0, 0, 0);
      }
      if (tap == 12) {
        const short8 qb = *(const short8*)&Bs[(34 << 9) + (lane << 3)];
#pragma unroll
        for (int f = 0; f < 4; ++f)
          aq[f] = __builtin_amdgcn_mfma_f32_16x16x32_bf16(a[f], qb, aq[f],
                                                          0, 0, 0);
      }
    }
  }
  // ---- epilogues (R13-verified algebra; nb extended for Tm=256) ----
#pragma unroll
  for (int rr2 = 0; rr2 < 2; ++rr2) {
#pragma unroll
    for (int ch = 0; ch < 2; ++ch) {
      const int f = (rr2 << 1) + ch;
      const int co = co0 + l15;
      const int slab = (b << 4) + (co >> 4);
      const int clo = co & 15;
      const int nb = n0 + (wv << 6) + (rr2 << 5) + (ch << 4) + (quad << 2);
      {
        const float bj = bc[co];
        floatx4 a = aq[f];
        ushort4 pk4;
        pk4.x = f2bf(a[0] + bj); pk4.y = f2bf(a[1] + bj);
        pk4.z = f2bf(a[2] + bj); pk4.w = f2bf(a[3] + bj);
        *(ushort4*)&qOut[(slab << 14) + (clo << 10) + nb] = pk4;
      }
      {
        const float bj = bc[512 + co];
        floatx4 a = ak[f];
        ushort4 pk4;
        pk4.x = f2bf(a[0] + bj); pk4.y = f2bf(a[1] + bj);
        pk4.z = f2bf(a[2] + bj); pk4.w = f2bf(a[3] + bj);
        *(ushort4*)&kOut[(slab << 14) + (clo << 10) + nb] = pk4;
      }
      {
        const float bj = bc[256 + co];
        floatx4 a = av[f];
        const int base = (slab << 14) + (clo << 6);
#pragma unroll
        for (int i = 0; i < 4; ++i) {
          const int n = nb + i;
          vOut[base + ((n & 15) << 10) + (n >> 4)] = f2bf(a[i] + bj);
        }
      }
    }
  }
}

// ---------------------------------------------------------------------------
// MFMA attention per (b,h) slab: softmax(Q K^T * 0.25) V.  [R5-verified]
//   qg, kg : bf16 [slab][1024 m][16 d];  vg : bf16 [slab][16 d][1024 m]
//   out2   : bf16 [8][1024 m][256], c = h*16+d
// ---------------------------------------------------------------------------
__global__ __launch_bounds__(256) void attn_mfma_kernel(
    const unsigned short* __restrict__ qg,
    const unsigned short* __restrict__ kg,
    const unsigned short* __restrict__ vg,
    unsigned short* __restrict__ out2) {
  __shared__ __align__(16) unsigned short Kc[16384];     // [key][16]
  __shared__ __align__(16) unsigned short Vt[16][1032];  // [d][key], padded
  __shared__ __align__(16) unsigned short Pb[4][32][40]; // per-wave P
  __shared__ float lb[4][32];
  const int t    = threadIdx.x;
  const int w    = t >> 6;
  const int lane = t & 63;
  const int slab = blockIdx.x >> 3;
  const int rb   = blockIdx.x & 7;
  const int b = slab >> 4;
  const int h = slab & 15;
  const int l31  = lane & 31;
  const int hl   = lane >> 5;
  const int l15  = lane & 15;
  const int quad = lane >> 4;

#pragma unroll
  for (int j = 0; j < 8; ++j) {
    const int id = (j << 8) + t;
    const int e  = id << 3;
    *(uint4*)&Kc[e] = *(const uint4*)&kg[(slab << 14) + e];
    const int d = e >> 10, ky = e & 1023;
    *(uint4*)&Vt[d][ky] = *(const uint4*)&vg[(slab << 14) + e];
  }

  const int row0 = (rb << 7) + (w << 5);
  const short8 qa =
      *(const short8*)&qg[(slab << 14) + ((row0 + l31) << 4) + (hl << 3)];

  float lsum[16] = {};
  floatx4 acco[2] = {};
  const float sc = 0.25f * 1.4426950408889634f;

  __syncthreads();

  for (int kc = 0; kc < 1024; kc += 32) {
    const short8 kb = *(const short8*)&Kc[((kc + l31) << 4) + (hl << 3)];
    floatx16 s = {};
    s = __builtin_amdgcn_mfma_f32_32x32x16_bf16(qa, kb, s, 0, 0, 0);
#pragma unroll
    for (int r = 0; r < 16; ++r) {
      const float e = exp2f(s[r] * sc);
      lsum[r] += e;
      const int row = (r & 3) + ((r >> 2) << 3) + (hl << 2);
      Pb[w][row][l31] = f2bf(e);
    }
    const short8 vb = *(const short8*)&Vt[l15][kc + (quad << 3)];
#pragma unroll
    for (int tt = 0; tt < 2; ++tt) {
      const short8 pa = *(const short8*)&Pb[w][(tt << 4) + l15][quad << 3];
      acco[tt] =
          __builtin_amdgcn_mfma_f32_16x16x32_bf16(pa, vb, acco[tt], 0, 0, 0);
    }
  }

#pragma unroll
  for (int r = 0; r < 16; ++r) {
    float lv = lsum[r];
    lv += __shfl_xor(lv, 1, 64);
    lv += __shfl_xor(lv, 2, 64);
    lv += __shfl_xor(lv, 4, 64);
    lv += __shfl_xor(lv, 8, 64);
    lv += __shfl_xor(lv, 16, 64);
    lsum[r] = lv;
  }
  {
    const int rr = l31;
    if (((rr >> 2) & 1) == hl) {
      const int reg = (rr & 3) + ((rr >> 3) << 2);
      lb[w][rr] = 1.0f / lsum[reg];
    }
  }
#pragma unroll
  for (int tt = 0; tt < 2; ++tt) {
#pragma unroll
    for (int r = 0; r < 4; ++r) {
      const int nloc = (tt << 4) + (quad << 2) + r;
      const float val = acco[tt][r] * lb[w][nloc];
      const int n = row0 + nloc;
      out2[(((b << 10) + n) << 8) + (h << 4) + l15] = f2bf(val);
    }
  }
}

// ---------------------------------------------------------------------------
// Final linear, MFMA bf16, with one-chunk-ahead B register prefetch.
// ---------------------------------------------------------------------------
__global__ __launch_bounds__(256) void linear_mfma_kernel(
    const unsigned short* __restrict__ inp,  // bf16 [8192][256]
    const unsigned short* __restrict__ wpF,  // fragment order
    void* __restrict__ out, const int* __restrict__ flag) {
  __shared__ unsigned short As[64 * 40];
  const int isf32 = *flag;
  const int t   = threadIdx.x;
  const int m0  = blockIdx.x << 6;
  const int co0 = blockIdx.y << 6;
  const int wv   = t >> 6;
  const int lane = t & 63;
  const int wm = (wv & 1) << 5;
  const int wn = (wv >> 1) << 5;
  const int l15  = lane & 15;
  const int quad = lane >> 4;
  const int cogb = (co0 >> 4) + (wn >> 4);
  const int rowS = t >> 2;
  const int partS = t & 3;

  floatx4 acc[2][2] = {};

  short8 cb0, cb1;
  {
    const unsigned short* wptr = &wpF[(cogb << 9) + (lane << 3)];
    cb0 = *(const short8*)wptr;
    cb1 = *(const short8*)(wptr + 512);
  }
  for (int c8 = 0; c8 < 8; ++c8) {
    const uint4 v = *(const uint4*)&inp[((m0 + rowS) << 8) + (c8 << 5) +
                                        (partS << 3)];
    short8 nb0 = {}, nb1 = {};
    if (c8 + 1 < 8) {
      const unsigned short* wptr =
          &wpF[((((c8 + 1) << 4) + cogb) << 9) + (lane << 3)];
      nb0 = *(const short8*)wptr;
      nb1 = *(const short8*)(wptr + 512);
    }
    __syncthreads();
    *(uint4*)&As[rowS * 40 + (partS << 3)] = v;
    __syncthreads();
    const unsigned short* xs = &As[(wm + l15) * 40 + (quad << 3)];
    const short8 afr0 = *(const short8*)xs;
    const short8 afr1 = *(const short8*)(xs + 16 * 40);
    acc[0][0] = __builtin_amdgcn_mfma_f32_16x16x32_bf16(afr0, cb0,
                                                        acc[0][0], 0, 0, 0);
    acc[0][1] = __builtin_amdgcn_mfma_f32_16x16x32_bf16(afr0, cb1,
                                                        acc[0][1], 0, 0, 0);
    acc[1][0] = __builtin_amdgcn_mfma_f32_16x16x32_bf16(afr1, cb0,
                                                        acc[1][0], 0, 0, 0);
    acc[1][1] = __builtin_amdgcn_mfma_f32_16x16x32_bf16(afr1, cb1,
                                                        acc[1][1], 0, 0, 0);
    cb0 = nb0; cb1 = nb1;
  }
#pragma unroll
  for (int mi = 0; mi < 2; ++mi) {
#pragma unroll
    for (int ni = 0; ni < 2; ++ni) {
      const int co = co0 + wn + (ni << 4) + l15;
      const int mb = m0 + wm + (mi << 4) + (quad << 2);
      floatx4 a = acc[mi][ni];
      if (!isf32) {
        unsigned short* o16 = (unsigned short*)out;
#pragma unroll
        for (int r = 0; r < 4; ++r) o16[(mb + r) * 256 + co] = f2bf(a[r]);
      } else {
        float* o32 = (float*)out;
#pragma unroll
        for (int r = 0; r < 4; ++r) o32[(mb + r) * 256 + co] = a[r];
      }
    }
  }
}

// ---------------------------------------------------------------------------
extern "C" void kernel_launch(void* const* d_in, const int* in_sizes, int n_in,
                              void* d_out, int out_size, void* d_ws,
                              size_t ws_size, hipStream_t stream) {
  const void* x  = d_in[0];
  const void* w3 = d_in[1];
  const void* b3 = d_in[2];
  const void* w5 = d_in[3];
  const void* b5 = d_in[4];
  const void* w7 = d_in[5];
  const void* b7 = d_in[6];
  const void* wp = d_in[7];

  char* p = (char*)d_ws;
  int* flag = (int*)p;                       p += 256;
  unsigned short* xbf = (unsigned short*)p;  p += 4u * 1024 * 1024;
  unsigned short* wF3 = (unsigned short*)p;  p += 131072;
  unsigned short* wF5 = (unsigned short*)p;  p += 1179648;
  unsigned short* wF7 = (unsigned short*)p;  p += 3276800;
  unsigned short* wpF = (unsigned short*)p;  p += 131072;
  float* bc = (float*)p;                     p += 4096;     // [3][256]
  unsigned short* qc  = (unsigned short*)p;  p += 4194304;  // bf16 QK rows
  unsigned short* kT  = (unsigned short*)p;  p += 4194304;  // bf16 QK rows
  unsigned short* vT  = (unsigned short*)p;  p += 4194304;  // bf16 V^T
  unsigned short* o2b = (unsigned short*)p;  p += 4194304;  // bf16 [8192][256]

  detect_kernel<<<1, 256, 0, stream>>>((const unsigned short*)x, flag);

  prep_kernel<<<11265, 256, 0, stream>>>(x, w3, b3, w5, b5, w7, b7, wp, xbf,
                                         wF3, wF5, wF7, wpF, bc, flag);

  convqkv_kernel<<<512, 256, 0, stream>>>(xbf, wF3, wF5, wF7, bc, qc, vT, kT);

  attn_mfma_kernel<<<1024, 256, 0, stream>>>(qc, kT, vT, o2b);

  dim3 lg(128, 4);
  linear_mfma_kernel<<<lg, 256, 0, stream>>>(o2b, wpF, d_out, flag);
}

// Round 16
// 181.212 us; speedup vs baseline: 1.2752x; 1.0801x over previous
//
#include <hip/hip_runtime.h>
#include <hip/hip_bf16.h>

#define DIM 256
#define HW  1024  // 32*32

typedef __attribute__((ext_vector_type(8))) short short8;
typedef __attribute__((ext_vector_type(4))) float floatx4;
typedef __attribute__((ext_vector_type(16))) float floatx16;
typedef __attribute__((address_space(1))) const unsigned int g_u32;
typedef __attribute__((address_space(3))) unsigned int l_u32;

// softmax scale folded into Q at conv epilogue: 0.25 * log2(e)
#define QSCALE 0.36067376022224085f

__device__ inline unsigned short f2bf(float f) {
  union { float f; unsigned u; } v;
  v.f = f;
  unsigned u = v.u;
  u += 0x7fffu + ((u >> 16) & 1u);
  return (unsigned short)(u >> 16);
}

// ---------------------------------------------------------------------------
// Dtype detector: flag=1 if inputs are fp32, 0 if bf16 (see R2 notes).
// ---------------------------------------------------------------------------
__global__ void detect_kernel(const unsigned short* __restrict__ xr,
                              int* __restrict__ flag) {
  __shared__ int cnt;
  if (threadIdx.x == 0) cnt = 0;
  __syncthreads();
  int local = 0;
  for (int i = threadIdx.x; i < 8192; i += 256) {
    unsigned short u = xr[i];
    if ((u & 0x7F80u) == 0x7F80u) local++;
  }
  if (local) atomicAdd(&cnt, local);
  __syncthreads();
  if (threadIdx.x == 0) *flag = (cnt > 0) ? 1 : 0;
}

__device__ inline float ldin(const void* p, long i, int isf32) {
  if (isf32) return ((const float*)p)[i];
  union { unsigned u; float f; } v;
  v.u = ((unsigned)((const unsigned short*)p)[i]) << 16;
  return v.f;
}

// ---------------------------------------------------------------------------
// R13 prep (verbatim): x->bf16, weights -> MFMA-fragment order bf16,
// biases -> fp32.
// wF layout: [tap][c8(8)][co16(16)][lane(64)][j(8)]  where
//   co = co16*16 + (lane&15), ci = c8*32 + (lane>>4)*8 + j
// ---------------------------------------------------------------------------
__device__ inline void frag_repack(const void* __restrict__ w,
                                   unsigned short* __restrict__ wF, int KK,
                                   int local_blk, int t, int isf32) {
  const int idx = local_blk * 256 + t;
  const int j    = idx & 7;
  const int lane = (idx >> 3) & 63;
  const int co16 = (idx >> 9) & 15;
  const int c8   = (idx >> 13) & 7;
  const int tap  = idx >> 16;
  const int co = (co16 << 4) | (lane & 15);
  const int ci = (c8 << 5) + ((lane >> 4) << 3) + j;
  wF[idx] = f2bf(ldin(w, (long)(co * 256 + ci) * KK + tap, isf32));
}

__global__ void prep_kernel(const void* __restrict__ x,
                            const void* __restrict__ w3,
                            const void* __restrict__ b3,
                            const void* __restrict__ w5,
                            const void* __restrict__ b5,
                            const void* __restrict__ w7,
                            const void* __restrict__ b7,
                            const void* __restrict__ wp,
                            unsigned short* __restrict__ xbf,
                            unsigned short* __restrict__ wF3,
                            unsigned short* __restrict__ wF5,
                            unsigned short* __restrict__ wF7,
                            unsigned short* __restrict__ wpF,
                            float* __restrict__ bc,  // [3][256] q,v,k
                            const int* __restrict__ flag) {
  const int isf32 = *flag;
  const int bid = blockIdx.x;
  const int t = threadIdx.x;
  if (bid < 2048) {            // x -> bf16, 4 elem/thread
    const int i = (bid * 256 + t) * 4;
    if (isf32) {
      const float4 v = *(const float4*)((const float*)x + i);
      ushort4 o;
      o.x = f2bf(v.x); o.y = f2bf(v.y); o.z = f2bf(v.z); o.w = f2bf(v.w);
      *(ushort4*)(xbf + i) = o;
    } else {
      *(ushort4*)(xbf + i) = *(const ushort4*)((const unsigned short*)x + i);
    }
  } else if (bid < 2304) {
    frag_repack(w3, wF3, 1, bid - 2048, t, isf32);
  } else if (bid < 4608) {
    frag_repack(w5, wF5, 9, bid - 2304, t, isf32);
  } else if (bid < 11008) {
    frag_repack(w7, wF7, 25, bid - 4608, t, isf32);
  } else if (bid < 11264) {
    frag_repack(wp, wpF, 1, bid - 11008, t, isf32);
  } else {                     // biases: 768 elements (q=b3, v=b5, k=b7)
#pragma unroll
    for (int r = 0; r < 3; ++r) {
      const int i = r * 256 + t;
      const void* src = (i < 256) ? b3 : (i < 512) ? b5 : b7;
      bc[i] = ldin(src, i & 255, isf32);
    }
  }
}

// ---------------------------------------------------------------------------
// R15-verified FUSED q/v/k conv, Tm=256 (wave owns 2 image rows, 4 A-frags).
// Only change (R16): q epilogue multiplies by QSCALE (softmax scale folded
// into Q — commutes with conv linearity), saving 16 v_mul/chunk in attn.
// B staged via global_load_lds(16B). LDS 71.4 KB -> 2 blocks/CU; grid 512.
// Attention coords (R2/R11-verified): slab=(b<<4)+(co>>4), m=(co&15)*64+(n>>4),
//   d=n&15;  q/k rows: (slab<<14)+((co&15)<<10)+n ;  v (V^T):
//   (slab<<14)+((n&15)<<10)+((co&15)<<6)+(n>>4)
// ---------------------------------------------------------------------------
__global__ __launch_bounds__(256, 2) void convqkv_kernel(
    const unsigned short* __restrict__ xbf,
    const unsigned short* __restrict__ wFq,  // 1 tap
    const unsigned short* __restrict__ wFv,  // 9 taps
    const unsigned short* __restrict__ wFk,  // 25 taps
    const float* __restrict__ bc,            // [3][256] q,v,k
    unsigned short* __restrict__ qOut,
    unsigned short* __restrict__ vOut,
    unsigned short* __restrict__ kOut) {
  constexpr int WC = 36;            // halo cols (32 + 2*2)
  constexpr int CELLS = 12 * WC;    // 12 halo rows (8 + 2*2) = 432 cells
  constexpr int LOADS = CELLS * 4;  // 1728 halo dwordx4 loads
  __shared__ unsigned short Xs[CELLS * 40];  // halo [cell][32ci pad40] 34.6KB
  __shared__ unsigned short Bs[36 * 512];    // B [tap35+1][lane64][8]  36.9KB
  const int t    = threadIdx.x;
  const int bid  = blockIdx.x;
  const int cog0 = bid & 15;           // single co16 tile (16 co)
  const int co0  = cog0 << 4;
  const int m0   = (bid >> 4) << 8;    // 256 positions (8 image rows)
  const int b    = m0 >> 10;
  const int n0   = m0 & 1023;
  const int r0   = n0 >> 5;            // first of 8 image rows
  const int wv   = t >> 6;             // wave owns rows r0+2wv, r0+2wv+1
  const int lane = t & 63;
  const int l15  = lane & 15;
  const int quad = lane >> 4;

  floatx4 aq[4] = {}, av[4] = {}, ak[4] = {};  // frag f = rr*2+ch

  for (int c8 = 0; c8 < 8; ++c8) {
    // ---- halo loads into registers (7 x uint4 = 28 VGPR; no spill) ----
    uint4 xreg[7];
#pragma unroll
    for (int rr = 0; rr < 7; ++rr) {
      const int id = rr * 256 + t;
      const int cell = id >> 2, part = id & 3;
      const int hr = cell / WC, wc = cell - hr * WC;
      const int xr = r0 + hr - 2, xc = wc - 2;
      const bool ok = (id < LOADS) && ((unsigned)xr < 32u) &&
                      ((unsigned)xc < 32u);
      const int cr = xr < 0 ? 0 : (xr > 31 ? 31 : xr);
      const int cc = xc < 0 ? 0 : (xc > 31 ? 31 : xc);
      uint4 v = *(const uint4*)&xbf[(((b * 32 + cr) * 32 + cc) << 8) +
                                    (c8 << 5) + (part << 3)];
      if (!ok) v = make_uint4(0, 0, 0, 0);
      xreg[rr] = v;
    }
    __syncthreads();  // ALL waves done reading previous chunk's Xs/Bs
    // ---- B: 35 taps via global_load_lds (wave-uniform base, lane*16B) ----
#pragma unroll
    for (int rr = 0; rr < 9; ++rr) {
      const int tap = (rr << 2) + wv;
      if (tap < 35) {
        const unsigned short* src;
        if (tap < 25) {
          src = &wFk[((((tap << 3) + c8) << 4) + cog0) * 512];
        } else if (tap < 34) {
          src = &wFv[(((((tap - 25) << 3) + c8) << 4) + cog0) * 512];
        } else {
          src = &wFq[((c8 << 4) + cog0) * 512];
        }
        __builtin_amdgcn_global_load_lds((g_u32*)(src + (lane << 3)),
                                         (l_u32*)&Bs[tap << 9], 16, 0, 0);
      }
    }
    // ---- halo regs -> LDS ----
#pragma unroll
    for (int rr = 0; rr < 7; ++rr) {
      const int id = rr * 256 + t;
      if (id < LOADS)
        *(uint4*)&Xs[(id >> 2) * 40 + ((id & 3) << 3)] = xreg[rr];
    }
    __syncthreads();  // drains vmcnt (glds) + lgkm (ds_writes): all ready

    // ---- tap loop: pure LDS + MFMA, no global, no barriers ----
#pragma unroll
    for (int tap = 0; tap < 25; ++tap) {
      const int kh = tap / 5, kw = tap % 5;
      const bool vv = (kh >= 1 && kh <= 3 && kw >= 1 && kw <= 3);
      short8 a[4];
#pragma unroll
      for (int rr2 = 0; rr2 < 2; ++rr2) {
#pragma unroll
        for (int ch = 0; ch < 2; ++ch) {
          const unsigned short* xs =
              &Xs[(((wv << 1) + rr2 + kh) * WC + (ch << 4) + l15 + kw) * 40 +
                  (quad << 3)];
          a[(rr2 << 1) + ch] = *(const short8*)xs;
        }
      }
      const short8 kb = *(const short8*)&Bs[(tap << 9) + (lane << 3)];
#pragma unroll
      for (int f = 0; f < 4; ++f)
        ak[f] = __builtin_amdgcn_mfma_f32_16x16x32_bf16(a[f], kb, ak[f],
                                                        0, 0, 0);
      if (vv) {
        const int vt = (kh - 1) * 3 + (kw - 1);
        const short8 vb = *(const short8*)&Bs[((25 + vt) << 9) + (lane << 3)];
#pragma unroll
        for (int f = 0; f < 4; ++f)
          av[f] = __builtin_amdgcn_mfma_f32_16x16x32_bf16(a[f], vb, av[f],
                                                          0, 0, 0);
      }
      if (tap == 12) {
        const short8 qb = *(const short8*)&Bs[(34 << 9) + (lane << 3)];
#pragma unroll
        for (int f = 0; f < 4; ++f)
          aq[f] = __builtin_amdgcn_mfma_f32_16x16x32_bf16(a[f], qb, aq[f],
                                                          0, 0, 0);
      }
    }
  }
  // ---- epilogues (R15-verified algebra; q scaled by QSCALE) ----
#pragma unroll
  for (int rr2 = 0; rr2 < 2; ++rr2) {
#pragma unroll
    for (int ch = 0; ch < 2; ++ch) {
      const int f = (rr2 << 1) + ch;
      const int co = co0 + l15;
      const int slab = (b << 4) + (co >> 4);
      const int clo = co & 15;
      const int nb = n0 + (wv << 6) + (rr2 << 5) + (ch << 4) + (quad << 2);
      {
        const float bj = bc[co];
        floatx4 a = aq[f];
        ushort4 pk4;
        pk4.x = f2bf((a[0] + bj) * QSCALE);
        pk4.y = f2bf((a[1] + bj) * QSCALE);
        pk4.z = f2bf((a[2] + bj) * QSCALE);
        pk4.w = f2bf((a[3] + bj) * QSCALE);
        *(ushort4*)&qOut[(slab << 14) + (clo << 10) + nb] = pk4;
      }
      {
        const float bj = bc[512 + co];
        floatx4 a = ak[f];
        ushort4 pk4;
        pk4.x = f2bf(a[0] + bj); pk4.y = f2bf(a[1] + bj);
        pk4.z = f2bf(a[2] + bj); pk4.w = f2bf(a[3] + bj);
        *(ushort4*)&kOut[(slab << 14) + (clo << 10) + nb] = pk4;
      }
      {
        const float bj = bc[256 + co];
        floatx4 a = av[f];
        const int base = (slab << 14) + (clo << 6);
#pragma unroll
        for (int i = 0; i < 4; ++i) {
          const int n = nb + i;
          vOut[base + ((n & 15) << 10) + (n >> 4)] = f2bf(a[i] + bj);
        }
      }
    }
  }
}

// ---------------------------------------------------------------------------
// R16 MFMA attention: VALU-diet + occupancy rebuild.
//   - Q pre-scaled (conv): e = exp2f(s) directly, no per-element mul.
//   - Row sums via ones-MFMA (B==1 makes B-layout irrelevant): kills the
//     16 adds/chunk and the entire 80-shuffle epilogue butterfly; numerator
//     and denominator share identical bf16-P rounding.
//   - K/V fragments read straight from global (L1/L2-resident slabs; K-frag
//     wave footprint = contiguous 1KB run). LDS = per-wave Pb only (10.2KB)
//     -> 4 blocks/CU resident, 4 waves/SIMD for the VALU-bound loop.
//   - Barrier-free: Pb is per-wave (wave-internal LDS ordering, R5-verified).
//   qg, kg : bf16 [slab][1024 m][16 d];  vg : bf16 [slab][16 d][1024 m]
//   out2   : bf16 [8][1024 m][256], c = h*16+d
// ---------------------------------------------------------------------------
__global__ __launch_bounds__(256, 4) void attn_mfma_kernel(
    const unsigned short* __restrict__ qg,
    const unsigned short* __restrict__ kg,
    const unsigned short* __restrict__ vg,
    unsigned short* __restrict__ out2) {
  __shared__ __align__(16) unsigned short Pb[4][32][40];  // per-wave P
  const int t    = threadIdx.x;
  const int w    = t >> 6;
  const int lane = t & 63;
  const int slab = blockIdx.x >> 3;
  const int rb   = blockIdx.x & 7;
  const int b = slab >> 4;
  const int h = slab & 15;
  const int l31  = lane & 31;
  const int hl   = lane >> 5;
  const int l15  = lane & 15;
  const int quad = lane >> 4;

  const unsigned short* Kb = kg + (slab << 14);
  const unsigned short* Vb = vg + (slab << 14);

  const int row0 = (rb << 7) + (w << 5);
  const short8 qa =
      *(const short8*)&qg[(slab << 14) + ((row0 + l31) << 4) + (hl << 3)];

  const short onebf = (short)0x3F80;  // bf16 1.0
  const short8 ones = {onebf, onebf, onebf, onebf, onebf, onebf, onebf, onebf};

  floatx4 acco[2] = {}, asum[2] = {};

  for (int kc = 0; kc < 1024; kc += 32) {
    const short8 kb = *(const short8*)&Kb[((kc + l31) << 4) + (hl << 3)];
    floatx16 s = {};
    s = __builtin_amdgcn_mfma_f32_32x32x16_bf16(qa, kb, s, 0, 0, 0);
#pragma unroll
    for (int r = 0; r < 16; ++r) {
      const float e = exp2f(s[r]);  // scale pre-folded into Q
      const int row = (r & 3) + ((r >> 2) << 3) + (hl << 2);
      Pb[w][row][l31] = f2bf(e);
    }
    const short8 vb = *(const short8*)&Vb[(l15 << 10) + kc + (quad << 3)];
#pragma unroll
    for (int tt = 0; tt < 2; ++tt) {
      const short8 pa = *(const short8*)&Pb[w][(tt << 4) + l15][quad << 3];
      acco[tt] =
          __builtin_amdgcn_mfma_f32_16x16x32_bf16(pa, vb, acco[tt], 0, 0, 0);
      asum[tt] =
          __builtin_amdgcn_mfma_f32_16x16x32_bf16(pa, ones, asum[tt], 0, 0, 0);
    }
  }
  // epilogue: C/D 16x16 layout col=l15=d, row=quad*4+r; asum[tt][r] holds the
  // row sum (same value in every column).
#pragma unroll
  for (int tt = 0; tt < 2; ++tt) {
#pragma unroll
    for (int r = 0; r < 4; ++r) {
      const int nloc = (tt << 4) + (quad << 2) + r;
      const float val = acco[tt][r] / asum[tt][r];
      const int n = row0 + nloc;
      out2[(((b << 10) + n) << 8) + (h << 4) + l15] = f2bf(val);
    }
  }
}

// ---------------------------------------------------------------------------
// Final linear, MFMA bf16, with one-chunk-ahead B register prefetch.
// ---------------------------------------------------------------------------
__global__ __launch_bounds__(256) void linear_mfma_kernel(
    const unsigned short* __restrict__ inp,  // bf16 [8192][256]
    const unsigned short* __restrict__ wpF,  // fragment order
    void* __restrict__ out, const int* __restrict__ flag) {
  __shared__ unsigned short As[64 * 40];
  const int isf32 = *flag;
  const int t   = threadIdx.x;
  const int m0  = blockIdx.x << 6;
  const int co0 = blockIdx.y << 6;
  const int wv   = t >> 6;
  const int lane = t & 63;
  const int wm = (wv & 1) << 5;
  const int wn = (wv >> 1) << 5;
  const int l15  = lane & 15;
  const int quad = lane >> 4;
  const int cogb = (co0 >> 4) + (wn >> 4);
  const int rowS = t >> 2;
  const int partS = t & 3;

  floatx4 acc[2][2] = {};

  short8 cb0, cb1;
  {
    const unsigned short* wptr = &wpF[(cogb << 9) + (lane << 3)];
    cb0 = *(const short8*)wptr;
    cb1 = *(const short8*)(wptr + 512);
  }
  for (int c8 = 0; c8 < 8; ++c8) {
    const uint4 v = *(const uint4*)&inp[((m0 + rowS) << 8) + (c8 << 5) +
                                        (partS << 3)];
    short8 nb0 = {}, nb1 = {};
    if (c8 + 1 < 8) {
      const unsigned short* wptr =
          &wpF[((((c8 + 1) << 4) + cogb) << 9) + (lane << 3)];
      nb0 = *(const short8*)wptr;
      nb1 = *(const short8*)(wptr + 512);
    }
    __syncthreads();
    *(uint4*)&As[rowS * 40 + (partS << 3)] = v;
    __syncthreads();
    const unsigned short* xs = &As[(wm + l15) * 40 + (quad << 3)];
    const short8 afr0 = *(const short8*)xs;
    const short8 afr1 = *(const short8*)(xs + 16 * 40);
    acc[0][0] = __builtin_amdgcn_mfma_f32_16x16x32_bf16(afr0, cb0,
                                                        acc[0][0], 0, 0, 0);
    acc[0][1] = __builtin_amdgcn_mfma_f32_16x16x32_bf16(afr0, cb1,
                                                        acc[0][1], 0, 0, 0);
    acc[1][0] = __builtin_amdgcn_mfma_f32_16x16x32_bf16(afr1, cb0,
                                                        acc[1][0], 0, 0, 0);
    acc[1][1] = __builtin_amdgcn_mfma_f32_16x16x32_bf16(afr1, cb1,
                                                        acc[1][1], 0, 0, 0);
    cb0 = nb0; cb1 = nb1;
  }
#pragma unroll
  for (int mi = 0; mi < 2; ++mi) {
#pragma unroll
    for (int ni = 0; ni < 2; ++ni) {
      const int co = co0 + wn + (ni << 4) + l15;
      const int mb = m0 + wm + (mi << 4) + (quad << 2);
      floatx4 a = acc[mi][ni];
      if (!isf32) {
        unsigned short* o16 = (unsigned short*)out;
#pragma unroll
        for (int r = 0; r < 4; ++r) o16[(mb + r) * 256 + co] = f2bf(a[r]);
      } else {
        float* o32 = (float*)out;
#pragma unroll
        for (int r = 0; r < 4; ++r) o32[(mb + r) * 256 + co] = a[r];
      }
    }
  }
}

// ---------------------------------------------------------------------------
extern "C" void kernel_launch(void* const* d_in, const int* in_sizes, int n_in,
                              void* d_out, int out_size, void* d_ws,
                              size_t ws_size, hipStream_t stream) {
  const void* x  = d_in[0];
  const void* w3 = d_in[1];
  const void* b3 = d_in[2];
  const void* w5 = d_in[3];
  const void* b5 = d_in[4];
  const void* w7 = d_in[5];
  const void* b7 = d_in[6];
  const void* wp = d_in[7];

  char* p = (char*)d_ws;
  int* flag = (int*)p;                       p += 256;
  unsigned short* xbf = (unsigned short*)p;  p += 4u * 1024 * 1024;
  unsigned short* wF3 = (unsigned short*)p;  p += 131072;
  unsigned short* wF5 = (unsigned short*)p;  p += 1179648;
  unsigned short* wF7 = (unsigned short*)p;  p += 3276800;
  unsigned short* wpF = (unsigned short*)p;  p += 131072;
  float* bc = (float*)p;                     p += 4096;     // [3][256]
  unsigned short* qc  = (unsigned short*)p;  p += 4194304;  // bf16 QK rows
  unsigned short* kT  = (unsigned short*)p;  p += 4194304;  // bf16 QK rows
  unsigned short* vT  = (unsigned short*)p;  p += 4194304;  // bf16 V^T
  unsigned short* o2b = (unsigned short*)p;  p += 4194304;  // bf16 [8192][256]

  detect_kernel<<<1, 256, 0, stream>>>((const unsigned short*)x, flag);

  prep_kernel<<<11265, 256, 0, stream>>>(x, w3, b3, w5, b5, w7, b7, wp, xbf,
                                         wF3, wF5, wF7, wpF, bc, flag);

  convqkv_kernel<<<512, 256, 0, stream>>>(xbf, wF3, wF5, wF7, bc, qc, vT, kT);

  attn_mfma_kernel<<<1024, 256, 0, stream>>>(qc, kT, vT, o2b);

  dim3 lg(128, 4);
  linear_mfma_kernel<<<lg, 256, 0, stream>>>(o2b, wpF, d_out, flag);
}

// Round 17
// 179.459 us; speedup vs baseline: 1.2877x; 1.0098x over previous
//
#include <hip/hip_runtime.h>
#include <hip/hip_bf16.h>

#define DIM 256
#define HW  1024  // 32*32

typedef __attribute__((ext_vector_type(8))) short short8;
typedef __attribute__((ext_vector_type(4))) float floatx4;
typedef __attribute__((ext_vector_type(16))) float floatx16;
typedef __attribute__((address_space(1))) const unsigned int g_u32;
typedef __attribute__((address_space(3))) unsigned int l_u32;

// softmax scale folded into Q at conv epilogue: 0.25 * log2(e)
#define QSCALE 0.36067376022224085f

__device__ inline unsigned short f2bf(float f) {
  union { float f; unsigned u; } v;
  v.f = f;
  unsigned u = v.u;
  u += 0x7fffu + ((u >> 16) & 1u);
  return (unsigned short)(u >> 16);
}

__device__ inline unsigned short f2bf_trunc(float f) {  // RTZ: 1 VALU inst
  union { float f; unsigned u; } v;
  v.f = f;
  return (unsigned short)(v.u >> 16);
}

// ---------------------------------------------------------------------------
// Dtype detector: flag=1 if inputs are fp32, 0 if bf16 (see R2 notes).
// ---------------------------------------------------------------------------
__global__ void detect_kernel(const unsigned short* __restrict__ xr,
                              int* __restrict__ flag) {
  __shared__ int cnt;
  if (threadIdx.x == 0) cnt = 0;
  __syncthreads();
  int local = 0;
  for (int i = threadIdx.x; i < 8192; i += 256) {
    unsigned short u = xr[i];
    if ((u & 0x7F80u) == 0x7F80u) local++;
  }
  if (local) atomicAdd(&cnt, local);
  __syncthreads();
  if (threadIdx.x == 0) *flag = (cnt > 0) ? 1 : 0;
}

__device__ inline float ldin(const void* p, long i, int isf32) {
  if (isf32) return ((const float*)p)[i];
  union { unsigned u; float f; } v;
  v.u = ((unsigned)((const unsigned short*)p)[i]) << 16;
  return v.f;
}

// ---------------------------------------------------------------------------
// R17 prep, de-confounded split:
//   xconv_kernel  : x -> bf16, 2048 blocks, ZERO LDS (streams at full occ).
//   wrepack_kernel: weights -> fragment order via R14's correctness-verified
//                   coalesced two-stage repack (51 KB LDS confined here),
//                   + bias block. Replaces the 100B-stride gather whose line
//                   amplification is the suspect for ~40us of hidden time.
// wF layout (unchanged): [tap][c8(8)][co16(16)][lane(64)][j(8)],
//   co = co16*16 + (lane&15), ci = c8*32 + (lane>>4)*8 + j.
// ---------------------------------------------------------------------------
__global__ __launch_bounds__(256) void xconv_kernel(
    const void* __restrict__ x, unsigned short* __restrict__ xbf,
    const int* __restrict__ flag) {
  const int isf32 = *flag;
  const int i = (blockIdx.x * 256 + threadIdx.x) * 4;
  if (isf32) {
    const float4 v = *(const float4*)((const float*)x + i);
    ushort4 o;
    o.x = f2bf(v.x); o.y = f2bf(v.y); o.z = f2bf(v.z); o.w = f2bf(v.w);
    *(ushort4*)(xbf + i) = o;
  } else {
    *(ushort4*)(xbf + i) = *(const ushort4*)((const unsigned short*)x + i);
  }
}

__device__ inline void frag_repack2(const void* __restrict__ w,
                                    unsigned short* __restrict__ wF, int KK,
                                    int slice, float* __restrict__ Wl,
                                    int isf32) {
  const int t = threadIdx.x;
  const int co16 = slice & 15;
  const int c8   = slice >> 4;
  const int RE = 32 * KK;  // elems per co row (contiguous in source)
  for (int r = 0; r < 16; ++r) {
    const long base = ((long)((co16 * 16 + r) * 256 + c8 * 32)) * KK;
    for (int i = t; i < RE; i += 256) Wl[r * RE + i] = ldin(w, base + i, isf32);
  }
  __syncthreads();
  for (int tap = 0; tap < KK; ++tap) {
    unsigned short* dst = wF + ((((tap << 3) + c8) << 4) + co16) * 512;
    for (int i = t; i < 512; i += 256) {
      const int lane = i >> 3, j = i & 7;
      const int col = lane & 15;
      const int cis = ((lane >> 4) << 3) + j;
      dst[i] = f2bf(Wl[(col * 32 + cis) * KK + tap]);
    }
  }
}

__global__ __launch_bounds__(256) void wrepack_kernel(
    const void* __restrict__ w3, const void* __restrict__ b3,
    const void* __restrict__ w5, const void* __restrict__ b5,
    const void* __restrict__ w7, const void* __restrict__ b7,
    const void* __restrict__ wp,
    unsigned short* __restrict__ wF3, unsigned short* __restrict__ wF5,
    unsigned short* __restrict__ wF7, unsigned short* __restrict__ wpF,
    float* __restrict__ bc, const int* __restrict__ flag) {
  __shared__ float Wl[12800];  // 16co x 32ci x 25tap max (51.2 KB)
  const int isf32 = *flag;
  const int bid = blockIdx.x;
  const int t = threadIdx.x;
  if (bid < 128) {
    frag_repack2(w7, wF7, 25, bid, Wl, isf32);
  } else if (bid < 256) {
    frag_repack2(w5, wF5, 9, bid - 128, Wl, isf32);
  } else if (bid < 384) {
    frag_repack2(w3, wF3, 1, bid - 256, Wl, isf32);
  } else if (bid < 512) {
    frag_repack2(wp, wpF, 1, bid - 384, Wl, isf32);
  } else {  // biases (q=b3, v=b5, k=b7)
#pragma unroll
    for (int r = 0; r < 3; ++r) {
      const int i = r * 256 + t;
      const void* src = (i < 256) ? b3 : (i < 512) ? b5 : b7;
      bc[i] = ldin(src, i & 255, isf32);
    }
  }
}

// ---------------------------------------------------------------------------
// R15/R16-verified FUSED q/v/k conv, Tm=256 (wave owns 2 image rows).
// q epilogue pre-scales by QSCALE (softmax fold). B via global_load_lds(16B).
// LDS 71.4 KB -> 2 blocks/CU; grid 512.
// Attention coords (R2/R11-verified): slab=(b<<4)+(co>>4), m=(co&15)*64+(n>>4),
//   d=n&15;  q/k rows: (slab<<14)+((co&15)<<10)+n ;  v (V^T):
//   (slab<<14)+((n&15)<<10)+((co&15)<<6)+(n>>4)
// ---------------------------------------------------------------------------
__global__ __launch_bounds__(256, 2) void convqkv_kernel(
    const unsigned short* __restrict__ xbf,
    const unsigned short* __restrict__ wFq,  // 1 tap
    const unsigned short* __restrict__ wFv,  // 9 taps
    const unsigned short* __restrict__ wFk,  // 25 taps
    const float* __restrict__ bc,            // [3][256] q,v,k
    unsigned short* __restrict__ qOut,
    unsigned short* __restrict__ vOut,
    unsigned short* __restrict__ kOut) {
  constexpr int WC = 36;            // halo cols (32 + 2*2)
  constexpr int CELLS = 12 * WC;    // 12 halo rows = 432 cells
  constexpr int LOADS = CELLS * 4;  // 1728 halo dwordx4 loads
  __shared__ unsigned short Xs[CELLS * 40];  // halo [cell][32ci pad40] 34.6KB
  __shared__ unsigned short Bs[36 * 512];    // B [tap35+1][lane64][8]  36.9KB
  const int t    = threadIdx.x;
  const int bid  = blockIdx.x;
  const int cog0 = bid & 15;
  const int co0  = cog0 << 4;
  const int m0   = (bid >> 4) << 8;    // 256 positions (8 image rows)
  const int b    = m0 >> 10;
  const int n0   = m0 & 1023;
  const int r0   = n0 >> 5;
  const int wv   = t >> 6;
  const int lane = t & 63;
  const int l15  = lane & 15;
  const int quad = lane >> 4;

  floatx4 aq[4] = {}, av[4] = {}, ak[4] = {};

  for (int c8 = 0; c8 < 8; ++c8) {
    uint4 xreg[7];
#pragma unroll
    for (int rr = 0; rr < 7; ++rr) {
      const int id = rr * 256 + t;
      const int cell = id >> 2, part = id & 3;
      const int hr = cell / WC, wc = cell - hr * WC;
      const int xr = r0 + hr - 2, xc = wc - 2;
      const bool ok = (id < LOADS) && ((unsigned)xr < 32u) &&
                      ((unsigned)xc < 32u);
      const int cr = xr < 0 ? 0 : (xr > 31 ? 31 : xr);
      const int cc = xc < 0 ? 0 : (xc > 31 ? 31 : xc);
      uint4 v = *(const uint4*)&xbf[(((b * 32 + cr) * 32 + cc) << 8) +
                                    (c8 << 5) + (part << 3)];
      if (!ok) v = make_uint4(0, 0, 0, 0);
      xreg[rr] = v;
    }
    __syncthreads();
#pragma unroll
    for (int rr = 0; rr < 9; ++rr) {
      const int tap = (rr << 2) + wv;
      if (tap < 35) {
        const unsigned short* src;
        if (tap < 25) {
          src = &wFk[((((tap << 3) + c8) << 4) + cog0) * 512];
        } else if (tap < 34) {
          src = &wFv[(((((tap - 25) << 3) + c8) << 4) + cog0) * 512];
        } else {
          src = &wFq[((c8 << 4) + cog0) * 512];
        }
        __builtin_amdgcn_global_load_lds((g_u32*)(src + (lane << 3)),
                                         (l_u32*)&Bs[tap << 9], 16, 0, 0);
      }
    }
#pragma unroll
    for (int rr = 0; rr < 7; ++rr) {
      const int id = rr * 256 + t;
      if (id < LOADS)
        *(uint4*)&Xs[(id >> 2) * 40 + ((id & 3) << 3)] = xreg[rr];
    }
    __syncthreads();

#pragma unroll
    for (int tap = 0; tap < 25; ++tap) {
      const int kh = tap / 5, kw = tap % 5;
      const bool vv = (kh >= 1 && kh <= 3 && kw >= 1 && kw <= 3);
      short8 a[4];
#pragma unroll
      for (int rr2 = 0; rr2 < 2; ++rr2) {
#pragma unroll
        for (int ch = 0; ch < 2; ++ch) {
          const unsigned short* xs =
              &Xs[(((wv << 1) + rr2 + kh) * WC + (ch << 4) + l15 + kw) * 40 +
                  (quad << 3)];
          a[(rr2 << 1) + ch] = *(const short8*)xs;
        }
      }
      const short8 kb = *(const short8*)&Bs[(tap << 9) + (lane << 3)];
#pragma unroll
      for (int f = 0; f < 4; ++f)
        ak[f] = __builtin_amdgcn_mfma_f32_16x16x32_bf16(a[f], kb, ak[f],
                                                        0, 0, 0);
      if (vv) {
        const int vt = (kh - 1) * 3 + (kw - 1);
        const short8 vb = *(const short8*)&Bs[((25 + vt) << 9) + (lane << 3)];
#pragma unroll
        for (int f = 0; f < 4; ++f)
          av[f] = __builtin_amdgcn_mfma_f32_16x16x32_bf16(a[f], vb, av[f],
                                                          0, 0, 0);
      }
      if (tap == 12) {
        const short8 qb = *(const short8*)&Bs[(34 << 9) + (lane << 3)];
#pragma unroll
        for (int f = 0; f < 4; ++f)
          aq[f] = __builtin_amdgcn_mfma_f32_16x16x32_bf16(a[f], qb, aq[f],
                                                          0, 0, 0);
      }
    }
  }
#pragma unroll
  for (int rr2 = 0; rr2 < 2; ++rr2) {
#pragma unroll
    for (int ch = 0; ch < 2; ++ch) {
      const int f = (rr2 << 1) + ch;
      const int co = co0 + l15;
      const int slab = (b << 4) + (co >> 4);
      const int clo = co & 15;
      const int nb = n0 + (wv << 6) + (rr2 << 5) + (ch << 4) + (quad << 2);
      {
        const float bj = bc[co];
        floatx4 a = aq[f];
        ushort4 pk4;
        pk4.x = f2bf((a[0] + bj) * QSCALE);
        pk4.y = f2bf((a[1] + bj) * QSCALE);
        pk4.z = f2bf((a[2] + bj) * QSCALE);
        pk4.w = f2bf((a[3] + bj) * QSCALE);
        *(ushort4*)&qOut[(slab << 14) + (clo << 10) + nb] = pk4;
      }
      {
        const float bj = bc[512 + co];
        floatx4 a = ak[f];
        ushort4 pk4;
        pk4.x = f2bf(a[0] + bj); pk4.y = f2bf(a[1] + bj);
        pk4.z = f2bf(a[2] + bj); pk4.w = f2bf(a[3] + bj);
        *(ushort4*)&kOut[(slab << 14) + (clo << 10) + nb] = pk4;
      }
      {
        const float bj = bc[256 + co];
        floatx4 a = av[f];
        const int base = (slab << 14) + (clo << 6);
#pragma unroll
        for (int i = 0; i < 4; ++i) {
          const int n = nb + i;
          vOut[base + ((n & 15) << 10) + (n >> 4)] = f2bf(a[i] + bj);
        }
      }
    }
  }
}

// ---------------------------------------------------------------------------
// R17 MFMA attention (R16 structure, VALU diet):
//   - __builtin_amdgcn_exp2f: guaranteed single v_exp_f32.
//   - Truncating bf16 P-store (1 inst vs ~4): truncation noise magnitude ==
//     existing RNE noise; mean bias cancels in the P/sum(P) ratio.
//   - Row sums via ones-MFMA; K/V straight from global; barrier-free;
//     LDS 10.2 KB -> 4 blocks/CU.
// ---------------------------------------------------------------------------
__global__ __launch_bounds__(256, 4) void attn_mfma_kernel(
    const unsigned short* __restrict__ qg,
    const unsigned short* __restrict__ kg,
    const unsigned short* __restrict__ vg,
    unsigned short* __restrict__ out2) {
  __shared__ __align__(16) unsigned short Pb[4][32][40];  // per-wave P
  const int t    = threadIdx.x;
  const int w    = t >> 6;
  const int lane = t & 63;
  const int slab = blockIdx.x >> 3;
  const int rb   = blockIdx.x & 7;
  const int b = slab >> 4;
  const int h = slab & 15;
  const int l31  = lane & 31;
  const int hl   = lane >> 5;
  const int l15  = lane & 15;
  const int quad = lane >> 4;

  const unsigned short* Kb = kg + (slab << 14);
  const unsigned short* Vb = vg + (slab << 14);

  const int row0 = (rb << 7) + (w << 5);
  const short8 qa =
      *(const short8*)&qg[(slab << 14) + ((row0 + l31) << 4) + (hl << 3)];

  const short onebf = (short)0x3F80;  // bf16 1.0
  const short8 ones = {onebf, onebf, onebf, onebf, onebf, onebf, onebf, onebf};

  floatx4 acco[2] = {}, asum[2] = {};

  for (int kc = 0; kc < 1024; kc += 32) {
    const short8 kb = *(const short8*)&Kb[((kc + l31) << 4) + (hl << 3)];
    floatx16 s = {};
    s = __builtin_amdgcn_mfma_f32_32x32x16_bf16(qa, kb, s, 0, 0, 0);
#pragma unroll
    for (int r = 0; r < 16; ++r) {
      const float e = __builtin_amdgcn_exp2f(s[r]);  // scale pre-folded in Q
      const int row = (r & 3) + ((r >> 2) << 3) + (hl << 2);
      Pb[w][row][l31] = f2bf_trunc(e);
    }
    const short8 vb = *(const short8*)&Vb[(l15 << 10) + kc + (quad << 3)];
#pragma unroll
    for (int tt = 0; tt < 2; ++tt) {
      const short8 pa = *(const short8*)&Pb[w][(tt << 4) + l15][quad << 3];
      acco[tt] =
          __builtin_amdgcn_mfma_f32_16x16x32_bf16(pa, vb, acco[tt], 0, 0, 0);
      asum[tt] =
          __builtin_amdgcn_mfma_f32_16x16x32_bf16(pa, ones, asum[tt], 0, 0, 0);
    }
  }
#pragma unroll
  for (int tt = 0; tt < 2; ++tt) {
#pragma unroll
    for (int r = 0; r < 4; ++r) {
      const int nloc = (tt << 4) + (quad << 2) + r;
      const float val = acco[tt][r] / asum[tt][r];
      const int n = row0 + nloc;
      out2[(((b << 10) + n) << 8) + (h << 4) + l15] = f2bf(val);
    }
  }
}

// ---------------------------------------------------------------------------
// Final linear, MFMA bf16, with one-chunk-ahead B register prefetch.
// ---------------------------------------------------------------------------
__global__ __launch_bounds__(256) void linear_mfma_kernel(
    const unsigned short* __restrict__ inp,  // bf16 [8192][256]
    const unsigned short* __restrict__ wpF,  // fragment order
    void* __restrict__ out, const int* __restrict__ flag) {
  __shared__ unsigned short As[64 * 40];
  const int isf32 = *flag;
  const int t   = threadIdx.x;
  const int m0  = blockIdx.x << 6;
  const int co0 = blockIdx.y << 6;
  const int wv   = t >> 6;
  const int lane = t & 63;
  const int wm = (wv & 1) << 5;
  const int wn = (wv >> 1) << 5;
  const int l15  = lane & 15;
  const int quad = lane >> 4;
  const int cogb = (co0 >> 4) + (wn >> 4);
  const int rowS = t >> 2;
  const int partS = t & 3;

  floatx4 acc[2][2] = {};

  short8 cb0, cb1;
  {
    const unsigned short* wptr = &wpF[(cogb << 9) + (lane << 3)];
    cb0 = *(const short8*)wptr;
    cb1 = *(const short8*)(wptr + 512);
  }
  for (int c8 = 0; c8 < 8; ++c8) {
    const uint4 v = *(const uint4*)&inp[((m0 + rowS) << 8) + (c8 << 5) +
                                        (partS << 3)];
    short8 nb0 = {}, nb1 = {};
    if (c8 + 1 < 8) {
      const unsigned short* wptr =
          &wpF[((((c8 + 1) << 4) + cogb) << 9) + (lane << 3)];
      nb0 = *(const short8*)wptr;
      nb1 = *(const short8*)(wptr + 512);
    }
    __syncthreads();
    *(uint4*)&As[rowS * 40 + (partS << 3)] = v;
    __syncthreads();
    const unsigned short* xs = &As[(wm + l15) * 40 + (quad << 3)];
    const short8 afr0 = *(const short8*)xs;
    const short8 afr1 = *(const short8*)(xs + 16 * 40);
    acc[0][0] = __builtin_amdgcn_mfma_f32_16x16x32_bf16(afr0, cb0,
                                                        acc[0][0], 0, 0, 0);
    acc[0][1] = __builtin_amdgcn_mfma_f32_16x16x32_bf16(afr0, cb1,
                                                        acc[0][1], 0, 0, 0);
    acc[1][0] = __builtin_amdgcn_mfma_f32_16x16x32_bf16(afr1, cb0,
                                                        acc[1][0], 0, 0, 0);
    acc[1][1] = __builtin_amdgcn_mfma_f32_16x16x32_bf16(afr1, cb1,
                                                        acc[1][1], 0, 0, 0);
    cb0 = nb0; cb1 = nb1;
  }
#pragma unroll
  for (int mi = 0; mi < 2; ++mi) {
#pragma unroll
    for (int ni = 0; ni < 2; ++ni) {
      const int co = co0 + wn + (ni << 4) + l15;
      const int mb = m0 + wm + (mi << 4) + (quad << 2);
      floatx4 a = acc[mi][ni];
      if (!isf32) {
        unsigned short* o16 = (unsigned short*)out;
#pragma unroll
        for (int r = 0; r < 4; ++r) o16[(mb + r) * 256 + co] = f2bf(a[r]);
      } else {
        float* o32 = (float*)out;
#pragma unroll
        for (int r = 0; r < 4; ++r) o32[(mb + r) * 256 + co] = a[r];
      }
    }
  }
}

// ---------------------------------------------------------------------------
extern "C" void kernel_launch(void* const* d_in, const int* in_sizes, int n_in,
                              void* d_out, int out_size, void* d_ws,
                              size_t ws_size, hipStream_t stream) {
  const void* x  = d_in[0];
  const void* w3 = d_in[1];
  const void* b3 = d_in[2];
  const void* w5 = d_in[3];
  const void* b5 = d_in[4];
  const void* w7 = d_in[5];
  const void* b7 = d_in[6];
  const void* wp = d_in[7];

  char* p = (char*)d_ws;
  int* flag = (int*)p;                       p += 256;
  unsigned short* xbf = (unsigned short*)p;  p += 4u * 1024 * 1024;
  unsigned short* wF3 = (unsigned short*)p;  p += 131072;
  unsigned short* wF5 = (unsigned short*)p;  p += 1179648;
  unsigned short* wF7 = (unsigned short*)p;  p += 3276800;
  unsigned short* wpF = (unsigned short*)p;  p += 131072;
  float* bc = (float*)p;                     p += 4096;     // [3][256]
  unsigned short* qc  = (unsigned short*)p;  p += 4194304;  // bf16 QK rows
  unsigned short* kT  = (unsigned short*)p;  p += 4194304;  // bf16 QK rows
  unsigned short* vT  = (unsigned short*)p;  p += 4194304;  // bf16 V^T
  unsigned short* o2b = (unsigned short*)p;  p += 4194304;  // bf16 [8192][256]

  detect_kernel<<<1, 256, 0, stream>>>((const unsigned short*)x, flag);

  xconv_kernel<<<2048, 256, 0, stream>>>(x, xbf, flag);
  wrepack_kernel<<<513, 256, 0, stream>>>(w3, b3, w5, b5, w7, b7, wp, wF3,
                                          wF5, wF7, wpF, bc, flag);

  convqkv_kernel<<<512, 256, 0, stream>>>(xbf, wF3, wF5, wF7, bc, qc, vT, kT);

  attn_mfma_kernel<<<1024, 256, 0, stream>>>(qc, kT, vT, o2b);

  dim3 lg(128, 4);
  linear_mfma_kernel<<<lg, 256, 0, stream>>>(o2b, wpF, d_out, flag);
}